// Round 18
// baseline (350.414 us; speedup 1.0000x reference)
//
#include <hip/hip_runtime.h>
#include <math.h>

#define N_IN   128
#define HC     128   // HEADS*OUT_CH
#define HEADS  4
#define PB_T   4096  // edges per partition tile
#define PB_THR 512   // threads in k_part
#define CAP    8192  // per-bucket edge capacity (mean 4096, sigma 64 -> +64s)
#define STB    1024  // k_stats blocks

typedef __attribute__((ext_vector_type(2))) __fp16 f16x2;
typedef __attribute__((ext_vector_type(8))) __fp16 f16x8;
typedef __attribute__((ext_vector_type(4))) float f32x4;

__device__ __forceinline__ unsigned f16pk(float a, float b) {
    f16x2 r = __builtin_amdgcn_cvt_pkrtz(a, b);
    return __builtin_bit_cast(unsigned, r);
}

// prep: Wt[n][k] = f16( n<128 ? Ws[k][n] : Wd[k][n-128] )   (Wt: [256][128])
__global__ __launch_bounds__(256) void k_prep(const float* __restrict__ Ws,
        const float* __restrict__ Wd, unsigned short* __restrict__ Wt) {
    int i = blockIdx.x * 256 + threadIdx.x;   // i = n*128 + k
    if (i >= 256 * 128) return;
    int n = i >> 7, k = i & 127;
    float v = (n < 128) ? Ws[k * HC + n] : Wd[k * HC + (n - 128)];
    __fp16 h = (__fp16)v;
    Wt[i] = __builtin_bit_cast(unsigned short, h);
}

// MFMA GEMM (f16), operand-swapped, fused f32->f16 convert of x in-kernel.
// D[ch][node]; packed 8-B stores.
__global__ __launch_bounds__(256) void k_gemm(const float* __restrict__ x,
        const __fp16* __restrict__ Wt,
        unsigned short* __restrict__ hs, unsigned short* __restrict__ hd, int N) {
    int wave = threadIdx.x >> 6, lane = threadIdx.x & 63;
    int chbase = wave * 64;
    int nbase = blockIdx.x * 32;
    int lr = lane & 15;
    int lg = lane >> 4;

    f16x8 a[4][4];
#pragma unroll
    for (int ct = 0; ct < 4; ct++)
#pragma unroll
        for (int kk = 0; kk < 4; kk++)
            a[ct][kk] = *reinterpret_cast<const f16x8*>(
                &Wt[(size_t)(chbase + ct * 16 + lr) * 128 + kk * 32 + lg * 8]);

    f32x4 acc[2][4];
#pragma unroll
    for (int rt = 0; rt < 2; rt++)
#pragma unroll
        for (int ct = 0; ct < 4; ct++)
            acc[rt][ct] = (f32x4){0.f, 0.f, 0.f, 0.f};

#pragma unroll
    for (int rt = 0; rt < 2; rt++) {
        int node = nbase + rt * 16 + lr;
        const float* xr = x + (size_t)node * N_IN;
        bool ok = (node < N);
        f16x8 bfr[4];
#pragma unroll
        for (int kk = 0; kk < 4; kk++) {
            f32x4 xa = (f32x4){0.f, 0.f, 0.f, 0.f}, xb = xa;
            if (ok) {
                xa = *reinterpret_cast<const f32x4*>(xr + kk * 32 + lg * 8);
                xb = *reinterpret_cast<const f32x4*>(xr + kk * 32 + lg * 8 + 4);
            }
            uint4 u;
            u.x = f16pk(xa[0], xa[1]); u.y = f16pk(xa[2], xa[3]);
            u.z = f16pk(xb[0], xb[1]); u.w = f16pk(xb[2], xb[3]);
            bfr[kk] = __builtin_bit_cast(f16x8, u);
        }
#pragma unroll
        for (int kk = 0; kk < 4; kk++)
#pragma unroll
            for (int ct = 0; ct < 4; ct++)
                acc[rt][ct] = __builtin_amdgcn_mfma_f32_16x16x32_f16(
                    a[ct][kk], bfr[kk], acc[rt][ct], 0, 0, 0);
    }

#pragma unroll
    for (int rt = 0; rt < 2; rt++) {
        int node = nbase + rt * 16 + lr;
        if (node >= N) continue;
#pragma unroll
        for (int ct = 0; ct < 4; ct++) {
            int ch = chbase + ct * 16 + lg * 4;
            unsigned short* outp = (ch < HC) ? hs : hd;
            int cc = ch & (HC - 1);
            uint2 r;
            r.x = f16pk(acc[rt][ct][0], acc[rt][ct][1]);
            r.y = f16pk(acc[rt][ct][2], acc[rt][ct][3]);
            *reinterpret_cast<uint2*>(outp + (size_t)node * HC + cc) = r;
        }
    }
}

// pass 1: partition edges into fixed-capacity dst-bucket segments of ebuf.
// packed entry: (src<<8) | (dst & 255).  bcur[b] counts edges per bucket.
__global__ __launch_bounds__(PB_THR) void k_part(const int* __restrict__ ei,
        int* __restrict__ bcur, unsigned* __restrict__ ebuf, int E, int NB) {
    __shared__ int cnt[512], lscan[512], gbase[512], lcnt[512];
    __shared__ unsigned pr[PB_T];
    __shared__ unsigned short pb[PB_T];
    int t = threadIdx.x;
    int tb = blockIdx.x * PB_T;
    int tc = min(PB_T, E - tb);
    cnt[t] = 0; lcnt[t] = 0;
    __syncthreads();
    int dd[8], ss[8];
#pragma unroll
    for (int i = 0; i < 8; i++) {
        int e = tb + t + i * PB_THR;
        if (e < E) {
            ss[i] = ei[e];
            dd[i] = ei[E + e];
            atomicAdd(&cnt[dd[i] >> 8], 1);
        } else dd[i] = -1;
    }
    __syncthreads();
    lscan[t] = cnt[t];
    __syncthreads();
    for (int ofs = 1; ofs < 512; ofs <<= 1) {
        int add = (t >= ofs) ? lscan[t - ofs] : 0;
        __syncthreads();
        lscan[t] += add;
        __syncthreads();
    }
    if (t < NB && cnt[t] > 0) gbase[t] = atomicAdd(&bcur[t], cnt[t]);
    __syncthreads();
#pragma unroll
    for (int i = 0; i < 8; i++) {
        if (dd[i] >= 0) {
            int b = dd[i] >> 8;
            int lpos = atomicAdd(&lcnt[b], 1);
            int j = lscan[b] - cnt[b] + lpos;
            pr[j] = ((unsigned)ss[i] << 8) | (unsigned)(dd[i] & 255);
            pb[j] = (unsigned short)b;
        }
    }
    __syncthreads();
    for (int k = t; k < tc; k += PB_THR) {
        int b = pb[k];
        ebuf[(size_t)b * CAP + gbase[b] + k - (lscan[b] - cnt[b])] = pr[k];
    }
}

// pass 2: one block per bucket. LDS histogram + scan -> deg/off (bucket-local),
// single-pass placement. ssrc stores src*256 (pre-scaled byte row offset).
__global__ __launch_bounds__(256) void k_place(const unsigned* __restrict__ ebuf,
        const int* __restrict__ bcur, int* __restrict__ deg, int* __restrict__ off,
        int* __restrict__ ssrc, int N) {
    __shared__ int hist[256], loff[256];
    int b = blockIdx.x;
    int t = threadIdx.x;
    int base = b * CAP;
    int cntb = bcur[b];
    hist[t] = 0;
    __syncthreads();
    for (int k = t; k < cntb; k += 256)
        atomicAdd(&hist[ebuf[base + k] & 255u], 1);
    __syncthreads();
    int v = hist[t];
    loff[t] = v;
    __syncthreads();
    for (int ofs = 1; ofs < 256; ofs <<= 1) {
        int add = (t >= ofs) ? loff[t - ofs] : 0;
        __syncthreads();
        loff[t] += add;
        __syncthreads();
    }
    int excl = loff[t] - v;
    int node = (b << 8) + t;
    if (node < N) { deg[node] = v; off[node] = base + excl; }
    hist[t] = base + excl;          // reuse as cursor
    __syncthreads();
    for (int k = t; k < cntb; k += 256) {
        unsigned u = ebuf[base + k];
        int pos = atomicAdd(&hist[u & 255u], 1);
        ssrc[pos] = (int)(u & 0xFFFFFF00u);   // src*256 = byte offset of row
    }
}

// ---- fused per-node aggregation: head-quarter split tied to XCD pairs ------
// wave = node x quarter Q (Q = one head = 64 B of the 256-B row).
// lane = e(16 edge slots)<<2 | cb(4 chunks of 8 ch).  Per edge: 16-B gather,
// 4 dot2 chain, butterfly xor1,2 over cb -> head dot; exp; 8 FMA.
// blockIdx%8 -> Q=(b>>1)&3 so each XCD streams only 6.4 MB of hs (L2-resident).
__global__ __launch_bounds__(256) void k_agg2(const unsigned short* __restrict__ hs,
        const unsigned short* __restrict__ hd, const int* __restrict__ off,
        const int* __restrict__ deg, const int* __restrict__ ssrc,
        const float* __restrict__ att, unsigned* __restrict__ outh,
        int N, int NBQ) {
    int b = blockIdx.x;
    int Q = (b >> 1) & 3;                  // XCDs {0,1}->Q0, {2,3}->Q1, ...
    int j = (b >> 3) * 2 + (b & 1);        // block rank within quarter
    if (j >= NBQ) return;
    int node = j * 4 + (threadIdx.x >> 6);
    if (node >= N) return;
    int lane = threadIdx.x & 63;
    int e  = lane >> 2;        // edge slot 0..15
    int cb = lane & 3;         // 8-ch chunk within quarter

    unsigned rowoff = (unsigned)(Q * 64 + cb * 16);   // byte offset in 256-B row
    const unsigned char* hsb = (const unsigned char*)hs;
    const unsigned char* hdb = (const unsigned char*)hd;

    // att chunk (8 ch) packed to f16
    int chbase = Q * 32 + cb * 8;
    f32x4 a0 = *reinterpret_cast<const f32x4*>(att + chbase);
    f32x4 a1 = *reinterpret_cast<const f32x4*>(att + chbase + 4);
    f16x2 at2[4];
    at2[0] = __builtin_bit_cast(f16x2, f16pk(a0[0], a0[1]));
    at2[1] = __builtin_bit_cast(f16x2, f16pk(a0[2], a0[3]));
    at2[2] = __builtin_bit_cast(f16x2, f16pk(a1[0], a1[1]));
    at2[3] = __builtin_bit_cast(f16x2, f16pk(a1[2], a1[3]));

    uint4 hu = *reinterpret_cast<const uint4*>(hdb + (size_t)node * 256u + rowoff);
    f16x2 hdv[4];
    hdv[0] = __builtin_bit_cast(f16x2, hu.x);
    hdv[1] = __builtin_bit_cast(f16x2, hu.y);
    hdv[2] = __builtin_bit_cast(f16x2, hu.z);
    hdv[3] = __builtin_bit_cast(f16x2, hu.w);

    float acc[8];
#pragma unroll
    for (int k = 0; k < 8; k++) acc[k] = 0.f;
    float ssum = 0.f;
    const f16x2 c02 = {(__fp16)0.2f, (__fp16)0.2f};

    auto process = [&](unsigned byteoff) {
        uint4 u = *reinterpret_cast<const uint4*>(hsb + byteoff);
        f16x2 v[4];
        v[0] = __builtin_bit_cast(f16x2, u.x);
        v[1] = __builtin_bit_cast(f16x2, u.y);
        v[2] = __builtin_bit_cast(f16x2, u.z);
        v[3] = __builtin_bit_cast(f16x2, u.w);
        float p = 0.f;
#pragma unroll
        for (int k = 0; k < 4; k++) {
            f16x2 s = v[k] + hdv[k];
            f16x2 t = __builtin_elementwise_max(s, s * c02);
            p = __builtin_amdgcn_fdot2(t, at2[k], p, false);
        }
        p += __shfl_xor(p, 1);
        p += __shfl_xor(p, 2);
        float ee = __expf(p);
        ssum += ee;
#pragma unroll
        for (int k = 0; k < 4; k++) {
            acc[2 * k]     += ee * (float)v[k][0];
            acc[2 * k + 1] += ee * (float)v[k][1];
        }
    };

    if (e == 0) process((unsigned)node * 256u + rowoff);   // self-loop once
    int beg = off[node], end = beg + deg[node];
    for (int i = beg + e; i < end; i += 16)
        process((unsigned)ssrc[i] + rowoff);

    // merge across the 16 edge slots
    ssum += __shfl_xor(ssum, 4);
    ssum += __shfl_xor(ssum, 8);
    ssum += __shfl_xor(ssum, 16);
    ssum += __shfl_xor(ssum, 32);
#pragma unroll
    for (int k = 0; k < 8; k++) {
        acc[k] += __shfl_xor(acc[k], 4);
        acc[k] += __shfl_xor(acc[k], 8);
        acc[k] += __shfl_xor(acc[k], 16);
        acc[k] += __shfl_xor(acc[k], 32);
    }
    if (e == 0) {
        float inv = 1.f / ssum;
        uint4 r;
        r.x = f16pk(acc[0] * inv, acc[1] * inv);
        r.y = f16pk(acc[2] * inv, acc[3] * inv);
        r.z = f16pk(acc[4] * inv, acc[5] * inv);
        r.w = f16pk(acc[6] * inv, acc[7] * inv);
        *reinterpret_cast<uint4*>(outh + (size_t)node * 64 + Q * 16 + cb * 4) = r;
    }
}

// per-channel sum & sumsq partials from f16 outh -> statp[block][256]
__global__ __launch_bounds__(256) void k_stats(const unsigned short* __restrict__ outh16,
        float* __restrict__ statp, int N) {
    int ch = threadIdx.x & 127;
    int half = threadIdx.x >> 7;
    float s = 0.f, s2 = 0.f;
    for (int n = blockIdx.x * 2 + half; n < N; n += gridDim.x * 2) {
        __fp16 h = __builtin_bit_cast(__fp16, outh16[(size_t)n * HC + ch]);
        float v = (float)h;
        s += v; s2 += v * v;
    }
    __shared__ float sh[2][256];
    sh[0][threadIdx.x] = s; sh[1][threadIdx.x] = s2;
    __syncthreads();
    if (threadIdx.x < 128) {
        size_t base = (size_t)blockIdx.x * 256;
        statp[base + threadIdx.x]       = sh[0][threadIdx.x] + sh[0][threadIdx.x + 128];
        statp[base + 128 + threadIdx.x] = sh[1][threadIdx.x] + sh[1][threadIdx.x + 128];
    }
}

// reduce per-block partials
__global__ __launch_bounds__(256) void k_redstats(const float* __restrict__ statp,
        float* __restrict__ stats, int NBLK) {
    int t = threadIdx.x;
    float acc = 0.f;
    for (int r = blockIdx.x; r < NBLK; r += gridDim.x)
        acc += statp[(size_t)r * 256 + t];
    atomicAdd(&stats[t], acc);
}

// fold stats into scale/shift
__global__ void k_bnparams(const float* __restrict__ stats,
        const float* __restrict__ gamma, const float* __restrict__ beta,
        float* __restrict__ ss, int N) {
    int c = threadIdx.x;
    if (c >= HC) return;
    float mean = stats[c] / (float)N;
    float var  = stats[HC + c] / (float)N - mean * mean;
    float sc = gamma[c] * rsqrtf(var + 1e-5f);
    ss[c]      = sc;
    ss[HC + c] = beta[c] - mean * sc;
}

// finalize: read f16 outh, BN affine + leaky(0.02), write f32 out
__global__ __launch_bounds__(256) void k_final(const unsigned short* __restrict__ outh16,
        const float* __restrict__ ss, float* __restrict__ out, int total) {
    int i = blockIdx.x * 256 + threadIdx.x;
    if (i >= total) return;
    int c = i & 127;
    __fp16 h = __builtin_bit_cast(__fp16, outh16[i]);
    float y = (float)h * ss[c] + ss[HC + c];
    out[i] = (y > 0.f) ? y : 0.02f * y;
}

extern "C" void kernel_launch(void* const* d_in, const int* in_sizes, int n_in,
                              void* d_out, int out_size, void* d_ws, size_t ws_size,
                              hipStream_t stream) {
    const float* x     = (const float*)d_in[0];
    const int*   ei    = (const int*)d_in[1];
    const float* Ws    = (const float*)d_in[2];
    const float* Wd    = (const float*)d_in[3];
    const float* att   = (const float*)d_in[4];
    // d_in[5] = bias: cancels exactly inside BatchNorm -> skipped
    const float* gamma = (const float*)d_in[6];
    const float* beta  = (const float*)d_in[7];
    float* out = (float*)d_out;

    int N  = in_sizes[0] / N_IN;
    int E  = in_sizes[1] / 2;
    int NB = (N + 255) >> 8;            // dst buckets (256 nodes each)
    int NBQ = (N + 3) / 4;              // blocks per quarter (4 nodes/block)
    int AGRID = 8 * ((NBQ + 1) / 2);    // total k_agg2 blocks (multiple of 8)

    char* ws = (char*)d_ws;
    unsigned short* hs = (unsigned short*)ws; ws += (size_t)N * HC * 2;
    unsigned short* hd = (unsigned short*)ws; ws += (size_t)N * HC * 2;
    unsigned* outh = (unsigned*)ws; ws += (size_t)N * HC * 2;
    int* deg    = (int*)ws;      ws += (size_t)N * 4;
    int* off    = (int*)ws;      ws += (size_t)N * 4;
    unsigned* ebuf = (unsigned*)ws; ws += (size_t)NB * CAP * 4;
    int* ssrc   = (int*)ws;      ws += (size_t)NB * CAP * 4;
    int* bcur   = (int*)ws;      ws += (size_t)NB * 4;
    unsigned short* Wt = (unsigned short*)ws; ws += 256 * 128 * 2;
    float* statp= (float*)ws;    ws += (size_t)STB * 256 * 4;
    float* stats= (float*)ws;    ws += 2 * HC * 4;
    float* ss   = (float*)ws;    ws += 2 * HC * 4;

    hipMemsetAsync(bcur, 0, (size_t)NB * 4, stream);
    hipMemsetAsync(stats, 0, 2 * HC * 4, stream);

    k_prep<<<128, 256, 0, stream>>>(Ws, Wd, Wt);
    k_gemm<<<(N + 31) / 32, 256, 0, stream>>>(x, (const __fp16*)Wt, hs, hd, N);
    k_part<<<(E + PB_T - 1) / PB_T, PB_THR, 0, stream>>>(ei, bcur, ebuf, E, NB);
    k_place<<<NB, 256, 0, stream>>>(ebuf, bcur, deg, off, ssrc, N);
    k_agg2<<<AGRID, 256, 0, stream>>>(hs, hd, off, deg, ssrc, att, outh, N, NBQ);
    k_stats<<<STB, 256, 0, stream>>>((const unsigned short*)outh, statp, N);
    k_redstats<<<64, 256, 0, stream>>>(statp, stats, STB);
    k_bnparams<<<1, 128, 0, stream>>>(stats, gamma, beta, ss, N);
    k_final<<<(N * HC + 255) / 256, 256, 0, stream>>>((const unsigned short*)outh, ss, out, N * HC);
}

// Round 19
// 213.671 us; speedup vs baseline: 1.6400x; 1.6400x over previous
//
#include <hip/hip_runtime.h>
#include <math.h>

#define N_IN   128
#define HC     128   // HEADS*OUT_CH
#define HEADS  4
#define PB_T   4096  // edges per partition tile
#define PB_THR 512   // threads in k_part
#define CAP    8192  // per-bucket edge capacity (mean 4096, sigma 64 -> +64s)
#define STB    1024  // k_stats blocks

typedef __attribute__((ext_vector_type(2))) __fp16 f16x2;
typedef __attribute__((ext_vector_type(8))) __fp16 f16x8;
typedef __attribute__((ext_vector_type(4))) float f32x4;

__device__ __forceinline__ unsigned f16pk(float a, float b) {
    f16x2 r = __builtin_amdgcn_cvt_pkrtz(a, b);
    return __builtin_bit_cast(unsigned, r);
}
__device__ __forceinline__ float2 h2f(unsigned u) {
    f16x2 h = __builtin_bit_cast(f16x2, u);
    return make_float2((float)h[0], (float)h[1]);
}

// prep: Wt[n][k] = f16 transpose of [Ws|Wd]; also zeroes stats and bcur
__global__ __launch_bounds__(256) void k_prep(const float* __restrict__ Ws,
        const float* __restrict__ Wd, unsigned short* __restrict__ Wt,
        float* __restrict__ stats, int* __restrict__ bcur, int NB) {
    int t = threadIdx.x;
    if (blockIdx.x == 0) stats[t] = 0.f;                       // 256 floats
    if (blockIdx.x == 1) for (int i = t; i < NB; i += 256) bcur[i] = 0;
    int i = blockIdx.x * 256 + t;   // i = n*128 + k
    if (i >= 256 * 128) return;
    int n = i >> 7, k = i & 127;
    float v = (n < 128) ? Ws[k * HC + n] : Wd[k * HC + (n - 128)];
    __fp16 h = (__fp16)v;
    Wt[i] = __builtin_bit_cast(unsigned short, h);
}

// MFMA GEMM (f16), operand-swapped, fused f32->f16 convert of x in-kernel.
// D[ch][node]; packed 8-B stores.
__global__ __launch_bounds__(256) void k_gemm(const float* __restrict__ x,
        const __fp16* __restrict__ Wt,
        unsigned short* __restrict__ hs, unsigned short* __restrict__ hd, int N) {
    int wave = threadIdx.x >> 6, lane = threadIdx.x & 63;
    int chbase = wave * 64;
    int nbase = blockIdx.x * 32;
    int lr = lane & 15;
    int lg = lane >> 4;

    f16x8 a[4][4];
#pragma unroll
    for (int ct = 0; ct < 4; ct++)
#pragma unroll
        for (int kk = 0; kk < 4; kk++)
            a[ct][kk] = *reinterpret_cast<const f16x8*>(
                &Wt[(size_t)(chbase + ct * 16 + lr) * 128 + kk * 32 + lg * 8]);

    f32x4 acc[2][4];
#pragma unroll
    for (int rt = 0; rt < 2; rt++)
#pragma unroll
        for (int ct = 0; ct < 4; ct++)
            acc[rt][ct] = (f32x4){0.f, 0.f, 0.f, 0.f};

#pragma unroll
    for (int rt = 0; rt < 2; rt++) {
        int node = nbase + rt * 16 + lr;
        const float* xr = x + (size_t)node * N_IN;
        bool ok = (node < N);
        f16x8 bfr[4];
#pragma unroll
        for (int kk = 0; kk < 4; kk++) {
            f32x4 xa = (f32x4){0.f, 0.f, 0.f, 0.f}, xb = xa;
            if (ok) {
                xa = *reinterpret_cast<const f32x4*>(xr + kk * 32 + lg * 8);
                xb = *reinterpret_cast<const f32x4*>(xr + kk * 32 + lg * 8 + 4);
            }
            uint4 u;
            u.x = f16pk(xa[0], xa[1]); u.y = f16pk(xa[2], xa[3]);
            u.z = f16pk(xb[0], xb[1]); u.w = f16pk(xb[2], xb[3]);
            bfr[kk] = __builtin_bit_cast(f16x8, u);
        }
#pragma unroll
        for (int kk = 0; kk < 4; kk++)
#pragma unroll
            for (int ct = 0; ct < 4; ct++)
                acc[rt][ct] = __builtin_amdgcn_mfma_f32_16x16x32_f16(
                    a[ct][kk], bfr[kk], acc[rt][ct], 0, 0, 0);
    }

#pragma unroll
    for (int rt = 0; rt < 2; rt++) {
        int node = nbase + rt * 16 + lr;
        if (node >= N) continue;
#pragma unroll
        for (int ct = 0; ct < 4; ct++) {
            int ch = chbase + ct * 16 + lg * 4;
            unsigned short* outp = (ch < HC) ? hs : hd;
            int cc = ch & (HC - 1);
            uint2 r;
            r.x = f16pk(acc[rt][ct][0], acc[rt][ct][1]);
            r.y = f16pk(acc[rt][ct][2], acc[rt][ct][3]);
            *reinterpret_cast<uint2*>(outp + (size_t)node * HC + cc) = r;
        }
    }
}

// pass 1: partition edges into fixed-capacity dst-bucket segments of ebuf.
// packed entry: (src<<8) | (dst & 255).  bcur[b] counts edges per bucket.
__global__ __launch_bounds__(PB_THR) void k_part(const int* __restrict__ ei,
        int* __restrict__ bcur, unsigned* __restrict__ ebuf, int E, int NB) {
    __shared__ int cnt[512], lscan[512], gbase[512], lcnt[512];
    __shared__ unsigned pr[PB_T];
    __shared__ unsigned short pb[PB_T];
    int t = threadIdx.x;
    int tb = blockIdx.x * PB_T;
    int tc = min(PB_T, E - tb);
    cnt[t] = 0; lcnt[t] = 0;
    __syncthreads();
    int dd[8], ss[8];
#pragma unroll
    for (int i = 0; i < 8; i++) {
        int e = tb + t + i * PB_THR;
        if (e < E) {
            ss[i] = ei[e];
            dd[i] = ei[E + e];
            atomicAdd(&cnt[dd[i] >> 8], 1);
        } else dd[i] = -1;
    }
    __syncthreads();
    lscan[t] = cnt[t];
    __syncthreads();
    for (int ofs = 1; ofs < 512; ofs <<= 1) {
        int add = (t >= ofs) ? lscan[t - ofs] : 0;
        __syncthreads();
        lscan[t] += add;
        __syncthreads();
    }
    if (t < NB && cnt[t] > 0) gbase[t] = atomicAdd(&bcur[t], cnt[t]);
    __syncthreads();
#pragma unroll
    for (int i = 0; i < 8; i++) {
        if (dd[i] >= 0) {
            int b = dd[i] >> 8;
            int lpos = atomicAdd(&lcnt[b], 1);
            int j = lscan[b] - cnt[b] + lpos;
            pr[j] = ((unsigned)ss[i] << 8) | (unsigned)(dd[i] & 255);
            pb[j] = (unsigned short)b;
        }
    }
    __syncthreads();
    for (int k = t; k < tc; k += PB_THR) {
        int b = pb[k];
        ebuf[(size_t)b * CAP + gbase[b] + k - (lscan[b] - cnt[b])] = pr[k];
    }
}

// pass 2: one block (512 thr) per bucket. LDS histogram + scan -> deg/off,
// single-pass placement. ssrc stores src*256 (pre-scaled byte row offset).
__global__ __launch_bounds__(512) void k_place(const unsigned* __restrict__ ebuf,
        const int* __restrict__ bcur, int* __restrict__ deg, int* __restrict__ off,
        int* __restrict__ ssrc, int N) {
    __shared__ int hist[256], loff[256];
    int b = blockIdx.x;
    int t = threadIdx.x;
    int base = b * CAP;
    int cntb = bcur[b];
    if (t < 256) hist[t] = 0;
    __syncthreads();
    for (int k = t; k < cntb; k += 512)
        atomicAdd(&hist[ebuf[base + k] & 255u], 1);
    __syncthreads();
    int v = (t < 256) ? hist[t] : 0;
    if (t < 256) loff[t] = v;
    __syncthreads();
    for (int ofs = 1; ofs < 256; ofs <<= 1) {
        int add = (t < 256 && t >= ofs) ? loff[t - ofs] : 0;
        __syncthreads();
        if (t < 256) loff[t] += add;
        __syncthreads();
    }
    if (t < 256) {
        int excl = loff[t] - v;
        int node = (b << 8) + t;
        if (node < N) { deg[node] = v; off[node] = base + excl; }
        hist[t] = base + excl;          // reuse as cursor
    }
    __syncthreads();
    for (int k = t; k < cntb; k += 512) {
        unsigned u = ebuf[base + k];
        int pos = atomicAdd(&hist[u & 255u], 1);
        ssrc[pos] = (int)(u & 0xFFFFFF00u);   // src*256 = byte offset of row
    }
}

// ---- fused per-node aggregation: channel-split halves tied to XCD ----------
// (R17-proven: half = 128 B = exactly one L2 line; quarter-split over-fetches)
__global__ __launch_bounds__(256) void k_agg2(const unsigned short* __restrict__ hs,
        const unsigned short* __restrict__ hd, const int* __restrict__ off,
        const int* __restrict__ deg, const int* __restrict__ ssrc,
        const float* __restrict__ att, unsigned* __restrict__ outh,
        int N, int NP) {
    int b = blockIdx.x;
    int H = (b >> 2) & 1;                  // blockIdx%8 in [0,4) -> 0, [4,8) -> 1
    int j = (b >> 3) * 4 + (b & 3);        // rank within half
    int pair = j * 4 + (threadIdx.x >> 6);
    if (pair >= NP) return;
    int lane = threadIdx.x & 63;
    int g  = lane >> 5;        // which node of the pair
    int e  = (lane >> 3) & 3;  // edge slot
    int cb = lane & 7;         // 8-channel block within the half
    int node = pair * 2 + g;
    if (node >= N) return;

    unsigned rowoff = (unsigned)(H * 128 + cb * 16);   // byte offset in 256-B row
    const unsigned char* hsb = (const unsigned char*)hs;
    const unsigned char* hdb = (const unsigned char*)hd;

    int chbase = H * 64 + cb * 8;
    f32x4 a0 = *reinterpret_cast<const f32x4*>(att + chbase);
    f32x4 a1 = *reinterpret_cast<const f32x4*>(att + chbase + 4);
    f16x2 at2[4];
    at2[0] = __builtin_bit_cast(f16x2, f16pk(a0[0], a0[1]));
    at2[1] = __builtin_bit_cast(f16x2, f16pk(a0[2], a0[3]));
    at2[2] = __builtin_bit_cast(f16x2, f16pk(a1[0], a1[1]));
    at2[3] = __builtin_bit_cast(f16x2, f16pk(a1[2], a1[3]));

    uint4 hu = *reinterpret_cast<const uint4*>(hdb + (size_t)node * 256u + rowoff);
    f16x2 hdv[4];
    hdv[0] = __builtin_bit_cast(f16x2, hu.x);
    hdv[1] = __builtin_bit_cast(f16x2, hu.y);
    hdv[2] = __builtin_bit_cast(f16x2, hu.z);
    hdv[3] = __builtin_bit_cast(f16x2, hu.w);

    float acc[8];
#pragma unroll
    for (int k = 0; k < 8; k++) acc[k] = 0.f;
    float ssum = 0.f;
    const f16x2 c02 = {(__fp16)0.2f, (__fp16)0.2f};

    auto process = [&](unsigned byteoff) {
        uint4 u = *reinterpret_cast<const uint4*>(hsb + byteoff);
        f16x2 v[4];
        v[0] = __builtin_bit_cast(f16x2, u.x);
        v[1] = __builtin_bit_cast(f16x2, u.y);
        v[2] = __builtin_bit_cast(f16x2, u.z);
        v[3] = __builtin_bit_cast(f16x2, u.w);
        float p = 0.f;
#pragma unroll
        for (int k = 0; k < 4; k++) {
            f16x2 s = v[k] + hdv[k];
            f16x2 t = __builtin_elementwise_max(s, s * c02);
            p = __builtin_amdgcn_fdot2(t, at2[k], p, false);
        }
        p += __shfl_xor(p, 1);
        p += __shfl_xor(p, 2);
        float ee = __expf(p);
        ssum += ee;
#pragma unroll
        for (int k = 0; k < 4; k++) {
            acc[2 * k]     += ee * (float)v[k][0];
            acc[2 * k + 1] += ee * (float)v[k][1];
        }
    };

    if (e == 0) process((unsigned)node * 256u + rowoff);   // self-loop once
    int beg = off[node], end = beg + deg[node];
    for (int i = beg + e; i < end; i += 4)
        process((unsigned)ssrc[i] + rowoff);

    // merge across the 4 edge slots (stays within this node's 32 lanes)
    ssum += __shfl_xor(ssum, 8);
    ssum += __shfl_xor(ssum, 16);
#pragma unroll
    for (int k = 0; k < 8; k++) {
        acc[k] += __shfl_xor(acc[k], 8);
        acc[k] += __shfl_xor(acc[k], 16);
    }
    if (e == 0) {
        float inv = 1.f / ssum;
        uint4 r;
        r.x = f16pk(acc[0] * inv, acc[1] * inv);
        r.y = f16pk(acc[2] * inv, acc[3] * inv);
        r.z = f16pk(acc[4] * inv, acc[5] * inv);
        r.w = f16pk(acc[6] * inv, acc[7] * inv);
        *reinterpret_cast<uint4*>(outh + (size_t)node * 64 + H * 32 + cb * 4) = r;
    }
}

// per-channel sum & sumsq partials from f16 outh (uint = 2ch loads)
__global__ __launch_bounds__(256) void k_stats(const unsigned* __restrict__ outh32,
        float* __restrict__ statp, int N) {
    int q = threadIdx.x >> 6;       // 4 row-groups
    int u = threadIdx.x & 63;       // uint index within row (2 channels)
    float s0 = 0.f, s1 = 0.f, q0 = 0.f, q1 = 0.f;
    for (int n = blockIdx.x * 4 + q; n < N; n += gridDim.x * 4) {
        float2 v = h2f(outh32[(size_t)n * 64 + u]);
        s0 += v.x; s1 += v.y;
        q0 += v.x * v.x; q1 += v.y * v.y;
    }
    __shared__ float sh[4][256];
    sh[0][threadIdx.x] = s0; sh[1][threadIdx.x] = s1;
    sh[2][threadIdx.x] = q0; sh[3][threadIdx.x] = q1;
    __syncthreads();
    if (threadIdx.x < 64) {
        size_t base = (size_t)blockIdx.x * 256;
        int t = threadIdx.x;
        float a0 = sh[0][t] + sh[0][t + 64] + sh[0][t + 128] + sh[0][t + 192];
        float a1 = sh[1][t] + sh[1][t + 64] + sh[1][t + 128] + sh[1][t + 192];
        float b0 = sh[2][t] + sh[2][t + 64] + sh[2][t + 128] + sh[2][t + 192];
        float b1 = sh[3][t] + sh[3][t + 64] + sh[3][t + 128] + sh[3][t + 192];
        statp[base + 2 * t]       = a0;
        statp[base + 2 * t + 1]   = a1;
        statp[base + 128 + 2 * t]     = b0;
        statp[base + 128 + 2 * t + 1] = b1;
    }
}

// reduce per-block partials
__global__ __launch_bounds__(256) void k_redstats(const float* __restrict__ statp,
        float* __restrict__ stats, int NBLK) {
    int t = threadIdx.x;
    float acc = 0.f;
    for (int r = blockIdx.x; r < NBLK; r += gridDim.x)
        acc += statp[(size_t)r * 256 + t];
    atomicAdd(&stats[t], acc);
}

// fold stats into scale/shift
__global__ void k_bnparams(const float* __restrict__ stats,
        const float* __restrict__ gamma, const float* __restrict__ beta,
        float* __restrict__ ss, int N) {
    int c = threadIdx.x;
    if (c >= HC) return;
    float mean = stats[c] / (float)N;
    float var  = stats[HC + c] / (float)N - mean * mean;
    float sc = gamma[c] * rsqrtf(var + 1e-5f);
    ss[c]      = sc;
    ss[HC + c] = beta[c] - mean * sc;
}

// finalize: read f16 outh (uint2 = 4ch), BN affine + leaky(0.02), write float4
__global__ __launch_bounds__(256) void k_final(const uint2* __restrict__ outh64,
        const float* __restrict__ ss, float* __restrict__ out, int nquad) {
    int i = blockIdx.x * 256 + threadIdx.x;
    if (i >= nquad) return;
    int c = (i & 31) * 4;
    uint2 v = outh64[i];
    float2 v0 = h2f(v.x), v1 = h2f(v.y);
    float y0 = v0.x * ss[c]     + ss[HC + c];
    float y1 = v0.y * ss[c + 1] + ss[HC + c + 1];
    float y2 = v1.x * ss[c + 2] + ss[HC + c + 2];
    float y3 = v1.y * ss[c + 3] + ss[HC + c + 3];
    f32x4 r;
    r[0] = (y0 > 0.f) ? y0 : 0.02f * y0;
    r[1] = (y1 > 0.f) ? y1 : 0.02f * y1;
    r[2] = (y2 > 0.f) ? y2 : 0.02f * y2;
    r[3] = (y3 > 0.f) ? y3 : 0.02f * y3;
    *reinterpret_cast<f32x4*>(out + (size_t)i * 4) = r;
}

extern "C" void kernel_launch(void* const* d_in, const int* in_sizes, int n_in,
                              void* d_out, int out_size, void* d_ws, size_t ws_size,
                              hipStream_t stream) {
    const float* x     = (const float*)d_in[0];
    const int*   ei    = (const int*)d_in[1];
    const float* Ws    = (const float*)d_in[2];
    const float* Wd    = (const float*)d_in[3];
    const float* att   = (const float*)d_in[4];
    // d_in[5] = bias: cancels exactly inside BatchNorm -> skipped
    const float* gamma = (const float*)d_in[6];
    const float* beta  = (const float*)d_in[7];
    float* out = (float*)d_out;

    int N  = in_sizes[0] / N_IN;
    int E  = in_sizes[1] / 2;
    int NB = (N + 255) >> 8;            // dst buckets (256 nodes each)
    int NP = (N + 1) / 2;               // node pairs
    int G4 = (NP + 3) / 4;              // blocks per half
    int AGRID = 8 * ((G4 + 3) / 4);     // total k_agg2 blocks (multiple of 8)

    char* ws = (char*)d_ws;
    unsigned short* hs = (unsigned short*)ws; ws += (size_t)N * HC * 2;
    unsigned short* hd = (unsigned short*)ws; ws += (size_t)N * HC * 2;
    unsigned* outh = (unsigned*)ws; ws += (size_t)N * HC * 2;
    int* deg    = (int*)ws;      ws += (size_t)N * 4;
    int* off    = (int*)ws;      ws += (size_t)N * 4;
    unsigned* ebuf = (unsigned*)ws; ws += (size_t)NB * CAP * 4;
    int* ssrc   = (int*)ws;      ws += (size_t)NB * CAP * 4;
    int* bcur   = (int*)ws;      ws += (size_t)NB * 4;
    unsigned short* Wt = (unsigned short*)ws; ws += 256 * 128 * 2;
    float* statp= (float*)ws;    ws += (size_t)STB * 256 * 4;
    float* stats= (float*)ws;    ws += 2 * HC * 4;
    float* ss   = (float*)ws;    ws += 2 * HC * 4;

    k_prep<<<128, 256, 0, stream>>>(Ws, Wd, Wt, stats, bcur, NB);
    k_gemm<<<(N + 31) / 32, 256, 0, stream>>>(x, (const __fp16*)Wt, hs, hd, N);
    k_part<<<(E + PB_T - 1) / PB_T, PB_THR, 0, stream>>>(ei, bcur, ebuf, E, NB);
    k_place<<<NB, 512, 0, stream>>>(ebuf, bcur, deg, off, ssrc, N);
    k_agg2<<<AGRID, 256, 0, stream>>>(hs, hd, off, deg, ssrc, att, outh, N, NP);
    k_stats<<<STB, 256, 0, stream>>>(outh, statp, N);
    k_redstats<<<64, 256, 0, stream>>>(statp, stats, STB);
    k_bnparams<<<1, 128, 0, stream>>>(stats, gamma, beta, ss, N);
    k_final<<<(N * HC / 4 + 255) / 256, 256, 0, stream>>>((const uint2*)outh, ss, out, N * HC / 4);
}

// Round 20
// 197.034 us; speedup vs baseline: 1.7784x; 1.0844x over previous
//
#include <hip/hip_runtime.h>
#include <math.h>

#define N_IN   128
#define HC     128   // HEADS*OUT_CH
#define HEADS  4
#define PB_T   4096  // edges per partition tile
#define PB_THR 512   // threads in k_part
#define CAP    8192  // per-bucket edge capacity (mean 4096, sigma 64 -> +64s)
#define STB    1024  // k_stats blocks

typedef __attribute__((ext_vector_type(2))) __fp16 f16x2;
typedef __attribute__((ext_vector_type(8))) __fp16 f16x8;
typedef __attribute__((ext_vector_type(4))) float f32x4;

__device__ __forceinline__ unsigned f16pk(float a, float b) {
    f16x2 r = __builtin_amdgcn_cvt_pkrtz(a, b);
    return __builtin_bit_cast(unsigned, r);
}
__device__ __forceinline__ float2 h2f(unsigned u) {
    f16x2 h = __builtin_bit_cast(f16x2, u);
    return make_float2((float)h[0], (float)h[1]);
}

// prep: Wt[n][k] = f16 transpose of [Ws|Wd]; zeroes stats, bcur, done-counter
__global__ __launch_bounds__(256) void k_prep(const float* __restrict__ Ws,
        const float* __restrict__ Wd, unsigned short* __restrict__ Wt,
        float* __restrict__ stats, int* __restrict__ bcur, int* __restrict__ ctr,
        int NB) {
    int t = threadIdx.x;
    if (blockIdx.x == 0) { stats[t] = 0.f; if (t == 0) ctr[0] = 0; }
    if (blockIdx.x == 1) for (int i = t; i < NB; i += 256) bcur[i] = 0;
    int i = blockIdx.x * 256 + t;   // i = n*128 + k
    if (i >= 256 * 128) return;
    int n = i >> 7, k = i & 127;
    float v = (n < 128) ? Ws[k * HC + n] : Wd[k * HC + (n - 128)];
    __fp16 h = (__fp16)v;
    Wt[i] = __builtin_bit_cast(unsigned short, h);
}

// MFMA GEMM (f16), operand-swapped; x converted ONCE per row into padded LDS
// tile (all 4 waves share it).  D[ch][node]; packed 8-B stores.
__global__ __launch_bounds__(256) void k_gemm(const float* __restrict__ x,
        const __fp16* __restrict__ Wt,
        unsigned short* __restrict__ hs, unsigned short* __restrict__ hd, int N) {
    __shared__ __fp16 xtile[32][136];   // +8 pad: fragment reads 2-way/bank
    int tid = threadIdx.x;
    int wave = tid >> 6, lane = tid & 63;
    int chbase = wave * 64;
    int nbase = blockIdx.x * 32;
    int lr = lane & 15;
    int lg = lane >> 4;

    // cooperative stage: thread -> (row = tid>>3, 16-ch chunk = tid&7)
    {
        int row = tid >> 3, ck = tid & 7;
        int node = nbase + row;
        f32x4 xa = (f32x4){0.f,0.f,0.f,0.f}, xb = xa, xc = xa, xd = xa;
        if (node < N) {
            const float* xr = x + (size_t)node * N_IN + ck * 16;
            xa = *reinterpret_cast<const f32x4*>(xr);
            xb = *reinterpret_cast<const f32x4*>(xr + 4);
            xc = *reinterpret_cast<const f32x4*>(xr + 8);
            xd = *reinterpret_cast<const f32x4*>(xr + 12);
        }
        uint4 u0, u1;
        u0.x = f16pk(xa[0], xa[1]); u0.y = f16pk(xa[2], xa[3]);
        u0.z = f16pk(xb[0], xb[1]); u0.w = f16pk(xb[2], xb[3]);
        u1.x = f16pk(xc[0], xc[1]); u1.y = f16pk(xc[2], xc[3]);
        u1.z = f16pk(xd[0], xd[1]); u1.w = f16pk(xd[2], xd[3]);
        unsigned short* dst = (unsigned short*)&xtile[row][ck * 16];
        *reinterpret_cast<uint4*>(dst)     = u0;
        *reinterpret_cast<uint4*>(dst + 8) = u1;
    }

    f16x8 a[4][4];
#pragma unroll
    for (int ct = 0; ct < 4; ct++)
#pragma unroll
        for (int kk = 0; kk < 4; kk++)
            a[ct][kk] = *reinterpret_cast<const f16x8*>(
                &Wt[(size_t)(chbase + ct * 16 + lr) * 128 + kk * 32 + lg * 8]);

    f32x4 acc[2][4];
#pragma unroll
    for (int rt = 0; rt < 2; rt++)
#pragma unroll
        for (int ct = 0; ct < 4; ct++)
            acc[rt][ct] = (f32x4){0.f, 0.f, 0.f, 0.f};

    __syncthreads();

#pragma unroll
    for (int rt = 0; rt < 2; rt++) {
        f16x8 bfr[4];
#pragma unroll
        for (int kk = 0; kk < 4; kk++)
            bfr[kk] = *reinterpret_cast<const f16x8*>(
                &xtile[rt * 16 + lr][kk * 32 + lg * 8]);
#pragma unroll
        for (int kk = 0; kk < 4; kk++)
#pragma unroll
            for (int ct = 0; ct < 4; ct++)
                acc[rt][ct] = __builtin_amdgcn_mfma_f32_16x16x32_f16(
                    a[ct][kk], bfr[kk], acc[rt][ct], 0, 0, 0);
    }

#pragma unroll
    for (int rt = 0; rt < 2; rt++) {
        int node = nbase + rt * 16 + lr;
        if (node >= N) continue;
#pragma unroll
        for (int ct = 0; ct < 4; ct++) {
            int ch = chbase + ct * 16 + lg * 4;
            unsigned short* outp = (ch < HC) ? hs : hd;
            int cc = ch & (HC - 1);
            uint2 r;
            r.x = f16pk(acc[rt][ct][0], acc[rt][ct][1]);
            r.y = f16pk(acc[rt][ct][2], acc[rt][ct][3]);
            *reinterpret_cast<uint2*>(outp + (size_t)node * HC + cc) = r;
        }
    }
}

// pass 1: partition edges into fixed-capacity dst-bucket segments of ebuf.
// packed entry: (src<<8) | (dst & 255).  bcur[b] counts edges per bucket.
__global__ __launch_bounds__(PB_THR) void k_part(const int* __restrict__ ei,
        int* __restrict__ bcur, unsigned* __restrict__ ebuf, int E, int NB) {
    __shared__ int cnt[512], lscan[512], gbase[512], lcnt[512];
    __shared__ unsigned pr[PB_T];
    __shared__ unsigned short pb[PB_T];
    int t = threadIdx.x;
    int tb = blockIdx.x * PB_T;
    int tc = min(PB_T, E - tb);
    cnt[t] = 0; lcnt[t] = 0;
    __syncthreads();
    int dd[8], ss[8];
#pragma unroll
    for (int i = 0; i < 8; i++) {
        int e = tb + t + i * PB_THR;
        if (e < E) {
            ss[i] = ei[e];
            dd[i] = ei[E + e];
            atomicAdd(&cnt[dd[i] >> 8], 1);
        } else dd[i] = -1;
    }
    __syncthreads();
    lscan[t] = cnt[t];
    __syncthreads();
    for (int ofs = 1; ofs < 512; ofs <<= 1) {
        int add = (t >= ofs) ? lscan[t - ofs] : 0;
        __syncthreads();
        lscan[t] += add;
        __syncthreads();
    }
    if (t < NB && cnt[t] > 0) gbase[t] = atomicAdd(&bcur[t], cnt[t]);
    __syncthreads();
#pragma unroll
    for (int i = 0; i < 8; i++) {
        if (dd[i] >= 0) {
            int b = dd[i] >> 8;
            int lpos = atomicAdd(&lcnt[b], 1);
            int j = lscan[b] - cnt[b] + lpos;
            pr[j] = ((unsigned)ss[i] << 8) | (unsigned)(dd[i] & 255);
            pb[j] = (unsigned short)b;
        }
    }
    __syncthreads();
    for (int k = t; k < tc; k += PB_THR) {
        int b = pb[k];
        ebuf[(size_t)b * CAP + gbase[b] + k - (lscan[b] - cnt[b])] = pr[k];
    }
}

// pass 2: one block (512 thr) per bucket. LDS histogram + scan -> deg/off,
// single-pass placement. ssrc stores src*256 (pre-scaled byte row offset).
__global__ __launch_bounds__(512) void k_place(const unsigned* __restrict__ ebuf,
        const int* __restrict__ bcur, int* __restrict__ deg, int* __restrict__ off,
        int* __restrict__ ssrc, int N) {
    __shared__ int hist[256], loff[256];
    int b = blockIdx.x;
    int t = threadIdx.x;
    int base = b * CAP;
    int cntb = bcur[b];
    if (t < 256) hist[t] = 0;
    __syncthreads();
    for (int k = t; k < cntb; k += 512)
        atomicAdd(&hist[ebuf[base + k] & 255u], 1);
    __syncthreads();
    int v = (t < 256) ? hist[t] : 0;
    if (t < 256) loff[t] = v;
    __syncthreads();
    for (int ofs = 1; ofs < 256; ofs <<= 1) {
        int add = (t < 256 && t >= ofs) ? loff[t - ofs] : 0;
        __syncthreads();
        if (t < 256) loff[t] += add;
        __syncthreads();
    }
    if (t < 256) {
        int excl = loff[t] - v;
        int node = (b << 8) + t;
        if (node < N) { deg[node] = v; off[node] = base + excl; }
        hist[t] = base + excl;          // reuse as cursor
    }
    __syncthreads();
    for (int k = t; k < cntb; k += 512) {
        unsigned u = ebuf[base + k];
        int pos = atomicAdd(&hist[u & 255u], 1);
        ssrc[pos] = (int)(u & 0xFFFFFF00u);   // src*256 = byte offset of row
    }
}

// ---- fused per-node aggregation: channel-split halves tied to XCD ----------
// (R17-proven: half = 128 B = exactly one L2 line; quarter-split over-fetches)
__global__ __launch_bounds__(256) void k_agg2(const unsigned short* __restrict__ hs,
        const unsigned short* __restrict__ hd, const int* __restrict__ off,
        const int* __restrict__ deg, const int* __restrict__ ssrc,
        const float* __restrict__ att, unsigned* __restrict__ outh,
        int N, int NP) {
    int b = blockIdx.x;
    int H = (b >> 2) & 1;                  // blockIdx%8 in [0,4) -> 0, [4,8) -> 1
    int j = (b >> 3) * 4 + (b & 3);        // rank within half
    int pair = j * 4 + (threadIdx.x >> 6);
    if (pair >= NP) return;
    int lane = threadIdx.x & 63;
    int g  = lane >> 5;        // which node of the pair
    int e  = (lane >> 3) & 3;  // edge slot
    int cb = lane & 7;         // 8-channel block within the half
    int node = pair * 2 + g;
    if (node >= N) return;

    unsigned rowoff = (unsigned)(H * 128 + cb * 16);   // byte offset in 256-B row
    const unsigned char* hsb = (const unsigned char*)hs;
    const unsigned char* hdb = (const unsigned char*)hd;

    int chbase = H * 64 + cb * 8;
    f32x4 a0 = *reinterpret_cast<const f32x4*>(att + chbase);
    f32x4 a1 = *reinterpret_cast<const f32x4*>(att + chbase + 4);
    f16x2 at2[4];
    at2[0] = __builtin_bit_cast(f16x2, f16pk(a0[0], a0[1]));
    at2[1] = __builtin_bit_cast(f16x2, f16pk(a0[2], a0[3]));
    at2[2] = __builtin_bit_cast(f16x2, f16pk(a1[0], a1[1]));
    at2[3] = __builtin_bit_cast(f16x2, f16pk(a1[2], a1[3]));

    uint4 hu = *reinterpret_cast<const uint4*>(hdb + (size_t)node * 256u + rowoff);
    f16x2 hdv[4];
    hdv[0] = __builtin_bit_cast(f16x2, hu.x);
    hdv[1] = __builtin_bit_cast(f16x2, hu.y);
    hdv[2] = __builtin_bit_cast(f16x2, hu.z);
    hdv[3] = __builtin_bit_cast(f16x2, hu.w);

    float acc[8];
#pragma unroll
    for (int k = 0; k < 8; k++) acc[k] = 0.f;
    float ssum = 0.f;
    const f16x2 c02 = {(__fp16)0.2f, (__fp16)0.2f};

    auto process = [&](unsigned byteoff) {
        uint4 u = *reinterpret_cast<const uint4*>(hsb + byteoff);
        f16x2 v[4];
        v[0] = __builtin_bit_cast(f16x2, u.x);
        v[1] = __builtin_bit_cast(f16x2, u.y);
        v[2] = __builtin_bit_cast(f16x2, u.z);
        v[3] = __builtin_bit_cast(f16x2, u.w);
        float p = 0.f;
#pragma unroll
        for (int k = 0; k < 4; k++) {
            f16x2 s = v[k] + hdv[k];
            f16x2 t = __builtin_elementwise_max(s, s * c02);
            p = __builtin_amdgcn_fdot2(t, at2[k], p, false);
        }
        p += __shfl_xor(p, 1);
        p += __shfl_xor(p, 2);
        float ee = __expf(p);
        ssum += ee;
#pragma unroll
        for (int k = 0; k < 4; k++) {
            acc[2 * k]     += ee * (float)v[k][0];
            acc[2 * k + 1] += ee * (float)v[k][1];
        }
    };

    if (e == 0) process((unsigned)node * 256u + rowoff);   // self-loop once
    int beg = off[node], end = beg + deg[node];
    for (int i = beg + e; i < end; i += 4)
        process((unsigned)ssrc[i] + rowoff);

    // merge across the 4 edge slots (stays within this node's 32 lanes)
    ssum += __shfl_xor(ssum, 8);
    ssum += __shfl_xor(ssum, 16);
#pragma unroll
    for (int k = 0; k < 8; k++) {
        acc[k] += __shfl_xor(acc[k], 8);
        acc[k] += __shfl_xor(acc[k], 16);
    }
    if (e == 0) {
        float inv = 1.f / ssum;
        uint4 r;
        r.x = f16pk(acc[0] * inv, acc[1] * inv);
        r.y = f16pk(acc[2] * inv, acc[3] * inv);
        r.z = f16pk(acc[4] * inv, acc[5] * inv);
        r.w = f16pk(acc[6] * inv, acc[7] * inv);
        *reinterpret_cast<uint4*>(outh + (size_t)node * 64 + H * 32 + cb * 4) = r;
    }
}

// per-channel sum & sumsq partials from f16 outh (uint = 2ch loads)
__global__ __launch_bounds__(256) void k_stats(const unsigned* __restrict__ outh32,
        float* __restrict__ statp, int N) {
    int q = threadIdx.x >> 6;       // 4 row-groups
    int u = threadIdx.x & 63;       // uint index within row (2 channels)
    float s0 = 0.f, s1 = 0.f, q0 = 0.f, q1 = 0.f;
    for (int n = blockIdx.x * 4 + q; n < N; n += gridDim.x * 4) {
        float2 v = h2f(outh32[(size_t)n * 64 + u]);
        s0 += v.x; s1 += v.y;
        q0 += v.x * v.x; q1 += v.y * v.y;
    }
    __shared__ float sh[4][256];
    sh[0][threadIdx.x] = s0; sh[1][threadIdx.x] = s1;
    sh[2][threadIdx.x] = q0; sh[3][threadIdx.x] = q1;
    __syncthreads();
    if (threadIdx.x < 64) {
        size_t base = (size_t)blockIdx.x * 256;
        int t = threadIdx.x;
        float a0 = sh[0][t] + sh[0][t + 64] + sh[0][t + 128] + sh[0][t + 192];
        float a1 = sh[1][t] + sh[1][t + 64] + sh[1][t + 128] + sh[1][t + 192];
        float b0 = sh[2][t] + sh[2][t + 64] + sh[2][t + 128] + sh[2][t + 192];
        float b1 = sh[3][t] + sh[3][t + 64] + sh[3][t + 128] + sh[3][t + 192];
        statp[base + 2 * t]       = a0;
        statp[base + 2 * t + 1]   = a1;
        statp[base + 128 + 2 * t]     = b0;
        statp[base + 128 + 2 * t + 1] = b1;
    }
}

// reduce per-block partials; LAST block also folds stats -> scale/shift
__global__ __launch_bounds__(256) void k_redstats(const float* __restrict__ statp,
        float* __restrict__ stats, const float* __restrict__ gamma,
        const float* __restrict__ beta, float* __restrict__ ss,
        int* __restrict__ ctr, int NBLK, int N) {
    int t = threadIdx.x;
    float acc = 0.f;
    for (int r = blockIdx.x; r < NBLK; r += gridDim.x)
        acc += statp[(size_t)r * 256 + t];
    atomicAdd(&stats[t], acc);
    __threadfence();
    __syncthreads();
    __shared__ int lastflag;
    if (t == 0) lastflag = (atomicAdd(ctr, 1) == (int)gridDim.x - 1);
    __syncthreads();
    if (lastflag && t < HC) {
        float sum = atomicAdd(&stats[t], 0.f);        // coherent read
        float sq  = atomicAdd(&stats[HC + t], 0.f);
        float mean = sum / (float)N;
        float var  = sq / (float)N - mean * mean;
        float sc = gamma[t] * rsqrtf(var + 1e-5f);
        ss[t]      = sc;
        ss[HC + t] = beta[t] - mean * sc;
    }
}

// finalize: read f16 outh (uint2 = 4ch), BN affine + leaky(0.02), write float4
__global__ __launch_bounds__(256) void k_final(const uint2* __restrict__ outh64,
        const float* __restrict__ ss, float* __restrict__ out, int nquad) {
    int i = blockIdx.x * 256 + threadIdx.x;
    if (i >= nquad) return;
    int c = (i & 31) * 4;
    uint2 v = outh64[i];
    float2 v0 = h2f(v.x), v1 = h2f(v.y);
    float y0 = v0.x * ss[c]     + ss[HC + c];
    float y1 = v0.y * ss[c + 1] + ss[HC + c + 1];
    float y2 = v1.x * ss[c + 2] + ss[HC + c + 2];
    float y3 = v1.y * ss[c + 3] + ss[HC + c + 3];
    f32x4 r;
    r[0] = (y0 > 0.f) ? y0 : 0.02f * y0;
    r[1] = (y1 > 0.f) ? y1 : 0.02f * y1;
    r[2] = (y2 > 0.f) ? y2 : 0.02f * y2;
    r[3] = (y3 > 0.f) ? y3 : 0.02f * y3;
    *reinterpret_cast<f32x4*>(out + (size_t)i * 4) = r;
}

extern "C" void kernel_launch(void* const* d_in, const int* in_sizes, int n_in,
                              void* d_out, int out_size, void* d_ws, size_t ws_size,
                              hipStream_t stream) {
    const float* x     = (const float*)d_in[0];
    const int*   ei    = (const int*)d_in[1];
    const float* Ws    = (const float*)d_in[2];
    const float* Wd    = (const float*)d_in[3];
    const float* att   = (const float*)d_in[4];
    // d_in[5] = bias: cancels exactly inside BatchNorm -> skipped
    const float* gamma = (const float*)d_in[6];
    const float* beta  = (const float*)d_in[7];
    float* out = (float*)d_out;

    int N  = in_sizes[0] / N_IN;
    int E  = in_sizes[1] / 2;
    int NB = (N + 255) >> 8;            // dst buckets (256 nodes each)
    int NP = (N + 1) / 2;               // node pairs
    int G4 = (NP + 3) / 4;              // blocks per half
    int AGRID = 8 * ((G4 + 3) / 4);     // total k_agg2 blocks (multiple of 8)

    char* ws = (char*)d_ws;
    unsigned short* hs = (unsigned short*)ws; ws += (size_t)N * HC * 2;
    unsigned short* hd = (unsigned short*)ws; ws += (size_t)N * HC * 2;
    unsigned* outh = (unsigned*)ws; ws += (size_t)N * HC * 2;
    int* deg    = (int*)ws;      ws += (size_t)N * 4;
    int* off    = (int*)ws;      ws += (size_t)N * 4;
    unsigned* ebuf = (unsigned*)ws; ws += (size_t)NB * CAP * 4;
    int* ssrc   = (int*)ws;      ws += (size_t)NB * CAP * 4;
    int* bcur   = (int*)ws;      ws += (size_t)NB * 4;
    int* ctr    = (int*)ws;      ws += 256;
    unsigned short* Wt = (unsigned short*)ws; ws += 256 * 128 * 2;
    float* statp= (float*)ws;    ws += (size_t)STB * 256 * 4;
    float* stats= (float*)ws;    ws += 2 * HC * 4;
    float* ss   = (float*)ws;    ws += 2 * HC * 4;

    k_prep<<<128, 256, 0, stream>>>(Ws, Wd, Wt, stats, bcur, ctr, NB);
    k_gemm<<<(N + 31) / 32, 256, 0, stream>>>(x, (const __fp16*)Wt, hs, hd, N);
    k_part<<<(E + PB_T - 1) / PB_T, PB_THR, 0, stream>>>(ei, bcur, ebuf, E, NB);
    k_place<<<NB, 512, 0, stream>>>(ebuf, bcur, deg, off, ssrc, N);
    k_agg2<<<AGRID, 256, 0, stream>>>(hs, hd, off, deg, ssrc, att, outh, N, NP);
    k_stats<<<STB, 256, 0, stream>>>(outh, statp, N);
    k_redstats<<<64, 256, 0, stream>>>(statp, stats, gamma, beta, ss, ctr, STB, N);
    k_final<<<(N * HC / 4 + 255) / 256, 256, 0, stream>>>((const uint2*)outh, ss, out, N * HC / 4);
}